// Round 17
// baseline (251.379 us; speedup 1.0000x reference)
//
#include <hip/hip_runtime.h>
#include <hip/hip_cooperative_groups.h>

namespace cg = cooperative_groups;

#define TT 768
#define KD 512
#define NC 1024
#define RLN2_2 2.8853900817779268f   // 2/ln(2)

typedef short short8 __attribute__((ext_vector_type(8)));
typedef float f32x4  __attribute__((ext_vector_type(4)));
typedef float f32x2  __attribute__((ext_vector_type(2)));

__device__ __forceinline__ float fast_exp2(float x) {
#if __has_builtin(__builtin_amdgcn_exp2f)
    return __builtin_amdgcn_exp2f(x);
#else
    return exp2f(x);
#endif
}
__device__ __forceinline__ float fast_rcp(float x) {
#if __has_builtin(__builtin_amdgcn_rcpf)
    return __builtin_amdgcn_rcpf(x);
#else
    return 1.0f / x;
#endif
}
__device__ __forceinline__ float fast_tanh(float x) {
    float e = fast_exp2(x * RLN2_2);
    return fmaf(-2.0f, fast_rcp(e + 1.0f), 1.0f);
}
__device__ __forceinline__ ushort f2bf(float f) {   // RNE f32->bf16
    uint u = __float_as_uint(f);
    u += 0x7fff + ((u >> 16) & 1);
    return (ushort)(u >> 16);
}

// ===========================================================================
// FUSED FRONT (cooperative): phase1 prep -> grid.sync -> phase2 gemm1 ->
// grid.sync -> phase3 gemm2.  Grid 768 x 256 (3 blocks/CU, co-resident).
// Prep transposes are WAVE-PRIVATE (in-order DS pipe, no barriers).
// GEMM phases: 32x32 tile per block, 4-wave K-split (kv sums k in
// [kv*128,+128)), partials combined via LDS overlay.
// ===========================================================================
__global__ __launch_bounds__(256) void k_front(
    const float* __restrict__ x, const float* __restrict__ foh,
    const float* __restrict__ fom, const float* __restrict__ hid2,
    const float* __restrict__ catBias, const float* __restrict__ hid2Bias,
    ushort* __restrict__ xb, ushort* __restrict__ b1t, ushort* __restrict__ h2t,
    ushort* __restrict__ act, float* __restrict__ pw)
{
    __shared__ float smem[4][32][33];        // 16896 B; reused as ps overlay
    cg::grid_group grid = cg::this_grid();
    const int bid = blockIdx.x, t = threadIdx.x;
    const int wv = t >> 6, lane = t & 63;

    // ---------------- Phase 1: prep (per-wave units, no barriers) ----------
    {
        const int u = bid * 4 + wv;          // 3072 wave-slots >= 1408 units
        if (u < 384) {
            int base = u * 1024 + lane * 16;
            #pragma unroll
            for (int q = 0; q < 4; ++q) {
                float4 v = *(const float4*)&x[base + q * 4];
                ushort4 o; o.x = f2bf(v.x); o.y = f2bf(v.y); o.z = f2bf(v.z); o.w = f2bf(v.w);
                *(ushort4*)&xb[base + q * 4] = o;
            }
        } else if (u < 1408) {
            int bb = u - 384;
            const float* src; ushort* dst; int R, C;
            if (bb < 256)      { src = foh;  dst = b1t;             R = 512;  C = 512; }
            else if (bb < 512) { src = fom;  dst = b1t + 512 * 512; R = 512;  C = 512; bb -= 256; }
            else               { src = hid2; dst = h2t;             R = 1024; C = 512; bb -= 512; }
            const int r0 = (bb >> 4) * 32, c0 = (bb & 15) * 32;
            const int ty = lane >> 3, tx = lane & 7;
            float (*tile)[33] = smem[wv];    // wave-private slice
            #pragma unroll
            for (int q = 0; q < 4; ++q) {
                float4 v = *(const float4*)&src[(r0 + ty + q * 8) * C + c0 + tx * 4];
                tile[ty + q * 8][tx * 4 + 0] = v.x;
                tile[ty + q * 8][tx * 4 + 1] = v.y;
                tile[ty + q * 8][tx * 4 + 2] = v.z;
                tile[ty + q * 8][tx * 4 + 3] = v.w;
            }
            // wave-internal DS ordering: writes complete before reads below
            #pragma unroll
            for (int q = 0; q < 4; ++q) {
                int cl = ty + q * 8;
                ushort4 o;
                o.x = f2bf(tile[tx * 4 + 0][cl]);
                o.y = f2bf(tile[tx * 4 + 1][cl]);
                o.z = f2bf(tile[tx * 4 + 2][cl]);
                o.w = f2bf(tile[tx * 4 + 3][cl]);
                *(ushort4*)&dst[(c0 + cl) * R + r0 + tx * 4] = o;
            }
        }
    }
    grid.sync();

    // ---------------- Phase 2: gemm1 (tanh epilogue -> act bf16) -----------
    {
        const int n0 = (bid & 31) * 32, m0 = (bid >> 5) * 32;
        const int lrow = lane & 15, lk = (lane >> 4) * 8;
        const int kbase = wv * 128;

        const ushort* pa0 = &xb[(m0 + lrow) * KD + kbase + lk];
        const ushort* pa1 = pa0 + 16 * KD;
        const ushort* pb0 = &b1t[(n0 + lrow) * KD + kbase + lk];
        const ushort* pb1 = pb0 + 16 * KD;

        f32x4 acc[2][2] = {};
        #pragma unroll
        for (int k0 = 0; k0 < 128; k0 += 32) {
            short8 a0 = *(const short8*)(pa0 + k0);
            short8 a1 = *(const short8*)(pa1 + k0);
            short8 b0 = *(const short8*)(pb0 + k0);
            short8 b1 = *(const short8*)(pb1 + k0);
            acc[0][0] = __builtin_amdgcn_mfma_f32_16x16x32_bf16(a0, b0, acc[0][0], 0, 0, 0);
            acc[0][1] = __builtin_amdgcn_mfma_f32_16x16x32_bf16(a0, b1, acc[0][1], 0, 0, 0);
            acc[1][0] = __builtin_amdgcn_mfma_f32_16x16x32_bf16(a1, b0, acc[1][0], 0, 0, 0);
            acc[1][1] = __builtin_amdgcn_mfma_f32_16x16x32_bf16(a1, b1, acc[1][1], 0, 0, 0);
        }
        float* ps = (float*)smem;            // [3][64][20] = 15360 B overlay
        if (wv >= 1) {
            float* p = ps + (wv - 1) * 1280 + lane * 20;
            *(f32x4*)&p[0]  = acc[0][0];
            *(f32x4*)&p[4]  = acc[0][1];
            *(f32x4*)&p[8]  = acc[1][0];
            *(f32x4*)&p[12] = acc[1][1];
        }
        __syncthreads();
        if (wv == 0) {
            #pragma unroll
            for (int q = 0; q < 3; ++q) {
                const float* p = ps + q * 1280 + lane * 20;
                acc[0][0] += *(const f32x4*)&p[0];
                acc[0][1] += *(const f32x4*)&p[4];
                acc[1][0] += *(const f32x4*)&p[8];
                acc[1][1] += *(const f32x4*)&p[12];
            }
            const int crow = (lane >> 4) * 4, ccol = lane & 15;
            #pragma unroll
            for (int nf = 0; nf < 2; ++nf) {
                int col = n0 + nf * 16 + ccol;
                float cb = catBias[col];
                #pragma unroll
                for (int mf = 0; mf < 2; ++mf) {
                    #pragma unroll
                    for (int r = 0; r < 4; ++r) {
                        int row = m0 + mf * 16 + crow + r;
                        act[row * NC + col] = f2bf(fast_tanh(acc[mf][nf][r] + cb));
                    }
                }
            }
        }
    }
    grid.sync();

    // ---------------- Phase 3: gemm2 (exp epilogue -> pw f32) --------------
    {
        const int n0 = (bid & 31) * 32, m0 = (bid >> 5) * 32;
        const bool top = ((bid & 31) < 16);
        const int koff = top ? 0 : 512;
        const int nc0  = top ? n0 : n0 - 512;
        const int lrow = lane & 15, lk = (lane >> 4) * 8;
        const int kbase = wv * 128;

        const ushort* pa0 = &act[(m0 + lrow) * NC + koff + kbase + lk];
        const ushort* pa1 = pa0 + 16 * NC;
        const ushort* pb0 = &h2t[(nc0 + lrow) * NC + koff + kbase + lk];
        const ushort* pb1 = pb0 + 16 * NC;

        f32x4 acc[2][2] = {};
        #pragma unroll
        for (int k0 = 0; k0 < 128; k0 += 32) {
            short8 a0 = *(const short8*)(pa0 + k0);
            short8 a1 = *(const short8*)(pa1 + k0);
            short8 b0 = *(const short8*)(pb0 + k0);
            short8 b1 = *(const short8*)(pb1 + k0);
            acc[0][0] = __builtin_amdgcn_mfma_f32_16x16x32_bf16(a0, b0, acc[0][0], 0, 0, 0);
            acc[0][1] = __builtin_amdgcn_mfma_f32_16x16x32_bf16(a0, b1, acc[0][1], 0, 0, 0);
            acc[1][0] = __builtin_amdgcn_mfma_f32_16x16x32_bf16(a1, b0, acc[1][0], 0, 0, 0);
            acc[1][1] = __builtin_amdgcn_mfma_f32_16x16x32_bf16(a1, b1, acc[1][1], 0, 0, 0);
        }
        float* ps = (float*)smem;
        if (wv >= 1) {
            float* p = ps + (wv - 1) * 1280 + lane * 20;
            *(f32x4*)&p[0]  = acc[0][0];
            *(f32x4*)&p[4]  = acc[0][1];
            *(f32x4*)&p[8]  = acc[1][0];
            *(f32x4*)&p[12] = acc[1][1];
        }
        __syncthreads();
        if (wv == 0) {
            #pragma unroll
            for (int q = 0; q < 3; ++q) {
                const float* p = ps + q * 1280 + lane * 20;
                acc[0][0] += *(const f32x4*)&p[0];
                acc[0][1] += *(const f32x4*)&p[4];
                acc[1][0] += *(const f32x4*)&p[8];
                acc[1][1] += *(const f32x4*)&p[12];
            }
            const int crow = (lane >> 4) * 4, ccol = lane & 15;
            #pragma unroll
            for (int nf = 0; nf < 2; ++nf) {
                int col = n0 + nf * 16 + ccol;
                float hb = top ? hid2Bias[col] : 0.0f;
                #pragma unroll
                for (int mf = 0; mf < 2; ++mf) {
                    #pragma unroll
                    for (int r = 0; r < 4; ++r) {
                        int row = m0 + mf * 16 + crow + r;
                        pw[row * NC + col] = fast_exp2(RLN2_2 * (acc[mf][nf][r] + hb));
                    }
                }
            }
        }
    }
}

// ===========================================================================
// FALLBACK kernels (r15 versions) -- used only if cooperative launch fails.
// ===========================================================================
__global__ __launch_bounds__(64) void k_prep(
    const float* __restrict__ x, const float* __restrict__ foh,
    const float* __restrict__ fom, const float* __restrict__ hid2,
    ushort* __restrict__ xb, ushort* __restrict__ b1t, ushort* __restrict__ h2t)
{
    const int b = blockIdx.x, lane = threadIdx.x;
    if (b < 384) {
        int base = b * 1024 + lane * 16;
        #pragma unroll
        for (int q = 0; q < 4; ++q) {
            float4 v = *(const float4*)&x[base + q * 4];
            ushort4 o; o.x = f2bf(v.x); o.y = f2bf(v.y); o.z = f2bf(v.z); o.w = f2bf(v.w);
            *(ushort4*)&xb[base + q * 4] = o;
        }
        return;
    }
    __shared__ float tile[32][33];
    int bb = b - 384;
    const float* src; ushort* dst; int R, C;
    if (bb < 256)      { src = foh;  dst = b1t;             R = 512;  C = 512; }
    else if (bb < 512) { src = fom;  dst = b1t + 512 * 512; R = 512;  C = 512; bb -= 256; }
    else               { src = hid2; dst = h2t;             R = 1024; C = 512; bb -= 512; }
    const int r0 = (bb >> 4) * 32, c0 = (bb & 15) * 32;
    const int ty = lane >> 3, tx = lane & 7;
    #pragma unroll
    for (int q = 0; q < 4; ++q) {
        float4 v = *(const float4*)&src[(r0 + ty + q * 8) * C + c0 + tx * 4];
        tile[ty + q * 8][tx * 4 + 0] = v.x;
        tile[ty + q * 8][tx * 4 + 1] = v.y;
        tile[ty + q * 8][tx * 4 + 2] = v.z;
        tile[ty + q * 8][tx * 4 + 3] = v.w;
    }
    __syncthreads();
    #pragma unroll
    for (int q = 0; q < 4; ++q) {
        int cl = ty + q * 8;
        ushort4 o;
        o.x = f2bf(tile[tx * 4 + 0][cl]);
        o.y = f2bf(tile[tx * 4 + 1][cl]);
        o.z = f2bf(tile[tx * 4 + 2][cl]);
        o.w = f2bf(tile[tx * 4 + 3][cl]);
        *(ushort4*)&dst[(c0 + cl) * R + r0 + tx * 4] = o;
    }
}

__global__ __launch_bounds__(128) void k_gemm1(
    const ushort* __restrict__ xb, const ushort* __restrict__ b1t,
    const float* __restrict__ catBias, ushort* __restrict__ act)
{
    __shared__ float ps[64][20];
    const int t = threadIdx.x;
    const int kv = t >> 6, lane = t & 63;
    const int n0 = blockIdx.x * 32;
    const int m0 = blockIdx.y * 32;
    const int lrow = lane & 15, lk = (lane >> 4) * 8;
    const int kbase = kv * 256;

    const ushort* pa0 = &xb[(m0 + lrow) * KD + kbase + lk];
    const ushort* pa1 = pa0 + 16 * KD;
    const ushort* pb0 = &b1t[(n0 + lrow) * KD + kbase + lk];
    const ushort* pb1 = pb0 + 16 * KD;

    f32x4 acc[2][2] = {};
    #pragma unroll 4
    for (int k0 = 0; k0 < 256; k0 += 32) {
        short8 a0 = *(const short8*)(pa0 + k0);
        short8 a1 = *(const short8*)(pa1 + k0);
        short8 b0 = *(const short8*)(pb0 + k0);
        short8 b1 = *(const short8*)(pb1 + k0);
        acc[0][0] = __builtin_amdgcn_mfma_f32_16x16x32_bf16(a0, b0, acc[0][0], 0, 0, 0);
        acc[0][1] = __builtin_amdgcn_mfma_f32_16x16x32_bf16(a0, b1, acc[0][1], 0, 0, 0);
        acc[1][0] = __builtin_amdgcn_mfma_f32_16x16x32_bf16(a1, b0, acc[1][0], 0, 0, 0);
        acc[1][1] = __builtin_amdgcn_mfma_f32_16x16x32_bf16(a1, b1, acc[1][1], 0, 0, 0);
    }
    if (kv == 1) {
        *(f32x4*)&ps[lane][0]  = acc[0][0];
        *(f32x4*)&ps[lane][4]  = acc[0][1];
        *(f32x4*)&ps[lane][8]  = acc[1][0];
        *(f32x4*)&ps[lane][12] = acc[1][1];
    }
    __syncthreads();
    if (kv == 0) {
        acc[0][0] += *(const f32x4*)&ps[lane][0];
        acc[0][1] += *(const f32x4*)&ps[lane][4];
        acc[1][0] += *(const f32x4*)&ps[lane][8];
        acc[1][1] += *(const f32x4*)&ps[lane][12];
        const int crow = (lane >> 4) * 4, ccol = lane & 15;
        #pragma unroll
        for (int nf = 0; nf < 2; ++nf) {
            int col = n0 + nf * 16 + ccol;
            float cb = catBias[col];
            #pragma unroll
            for (int mf = 0; mf < 2; ++mf) {
                #pragma unroll
                for (int r = 0; r < 4; ++r) {
                    int row = m0 + mf * 16 + crow + r;
                    act[row * NC + col] = f2bf(fast_tanh(acc[mf][nf][r] + cb));
                }
            }
        }
    }
}

__global__ __launch_bounds__(128) void k_gemm2(
    const ushort* __restrict__ act, const ushort* __restrict__ h2t,
    const float* __restrict__ hid2Bias, float* __restrict__ pw)
{
    __shared__ float ps[64][20];
    const int t = threadIdx.x;
    const int kv = t >> 6, lane = t & 63;
    const int n0 = blockIdx.x * 32;
    const int m0 = blockIdx.y * 32;
    const bool top = (blockIdx.x < 16);
    const int koff = top ? 0 : 512;
    const int nc0  = top ? n0 : n0 - 512;
    const int lrow = lane & 15, lk = (lane >> 4) * 8;
    const int kbase = kv * 256;

    const ushort* pa0 = &act[(m0 + lrow) * NC + koff + kbase + lk];
    const ushort* pa1 = pa0 + 16 * NC;
    const ushort* pb0 = &h2t[(nc0 + lrow) * NC + koff + kbase + lk];
    const ushort* pb1 = pb0 + 16 * NC;

    f32x4 acc[2][2] = {};
    #pragma unroll 4
    for (int k0 = 0; k0 < 256; k0 += 32) {
        short8 a0 = *(const short8*)(pa0 + k0);
        short8 a1 = *(const short8*)(pa1 + k0);
        short8 b0 = *(const short8*)(pb0 + k0);
        short8 b1 = *(const short8*)(pb1 + k0);
        acc[0][0] = __builtin_amdgcn_mfma_f32_16x16x32_bf16(a0, b0, acc[0][0], 0, 0, 0);
        acc[0][1] = __builtin_amdgcn_mfma_f32_16x16x32_bf16(a0, b1, acc[0][1], 0, 0, 0);
        acc[1][0] = __builtin_amdgcn_mfma_f32_16x16x32_bf16(a1, b0, acc[1][0], 0, 0, 0);
        acc[1][1] = __builtin_amdgcn_mfma_f32_16x16x32_bf16(a1, b1, acc[1][1], 0, 0, 0);
    }
    if (kv == 1) {
        *(f32x4*)&ps[lane][0]  = acc[0][0];
        *(f32x4*)&ps[lane][4]  = acc[0][1];
        *(f32x4*)&ps[lane][8]  = acc[1][0];
        *(f32x4*)&ps[lane][12] = acc[1][1];
    }
    __syncthreads();
    if (kv == 0) {
        acc[0][0] += *(const f32x4*)&ps[lane][0];
        acc[0][1] += *(const f32x4*)&ps[lane][4];
        acc[1][0] += *(const f32x4*)&ps[lane][8];
        acc[1][1] += *(const f32x4*)&ps[lane][12];
        const int crow = (lane >> 4) * 4, ccol = lane & 15;
        #pragma unroll
        for (int nf = 0; nf < 2; ++nf) {
            int col = n0 + nf * 16 + ccol;
            float hb = top ? hid2Bias[col] : 0.0f;
            #pragma unroll
            for (int mf = 0; mf < 2; ++mf) {
                #pragma unroll
                for (int r = 0; r < 4; ++r) {
                    int row = m0 + mf * 16 + crow + r;
                    pw[row * NC + col] = fast_exp2(RLN2_2 * (acc[mf][nf][r] + hb));
                }
            }
        }
    }
}

// ---------------------------------------------------------------------------
// Pairwise [FROZEN = r15 best]: 16x16 tile / 4-wave h-split / wave-private
// staging / no main-loop barriers / packed f32x2 math / w in LDS.
// Grid 2304 XCD-swz x 4 waves; VGPR <= 64 -> 32 waves/CU resident.
// ---------------------------------------------------------------------------
__global__ __launch_bounds__(256) void k_pair(
    const float* __restrict__ pw, const float* __restrict__ w,
    const float* __restrict__ outBias, float* __restrict__ out)
{
    __shared__ float Ea[4][16][18];
    __shared__ float Em[4][16][18];
    __shared__ float wl[512];

    const int t    = threadIdx.x;
    const int wv   = t >> 6, lane = t & 63;
    const int bid  = blockIdx.x;
    const int sw   = (bid & 7) * 288 + (bid >> 3);   // XCD swizzle (8 | 2304)
    const int it = sw / 48, jt = sw % 48;
    const int i0 = it * 16, j0 = jt * 16;
    const int hb0 = wv * 128;                        // this wave's h-quarter

    *(float2*)&wl[hb0 + lane * 2] = *(const float2*)&w[hb0 + lane * 2];
    float4 wa = *(const float4*)&w[lane * 8];
    float4 wb = *(const float4*)&w[lane * 8 + 4];
    float lsum = (wa.x + wa.y) + (wa.z + wa.w) + (wb.x + wb.y) + (wb.z + wb.w);
    #pragma unroll
    for (int d = 1; d < 64; d <<= 1) lsum += __shfl_xor(lsum, d, 64);

    const int sr = lane >> 2;            // 0..15
    const int sc = (lane & 3) * 4;       // 0..12
    const float* srcA = &pw[(i0 + sr) * NC + hb0 + sc];
    const float* srcM = &pw[(j0 + sr) * NC + 512 + hb0 + sc];

    const int li = lane >> 3, lj = lane & 7;

    float4 fa = *(const float4*)(srcA);
    float4 fm = *(const float4*)(srcM);

    const f32x2 one2 = {1.0f, 1.0f};
    f32x2 accA[2] = {}, accB[2] = {};

    #pragma unroll 1
    for (int c = 0; c < 8; ++c) {        // 8 chunks x 16 h
        const int hh = c * 16;
        *(float4*)&Ea[wv][sr][sc] = fa;  // wave-private; in-order DS pipe
        *(float4*)&Em[wv][sr][sc] = fm;
        if (c < 7) {
            fa = *(const float4*)(srcA + hh + 16);
            fm = *(const float4*)(srcM + hh + 16);
        }
        #pragma unroll
        for (int hq = 0; hq < 4; ++hq) {
            float4 e0 = *(const float4*)&Ea[wv][2 * li    ][hq * 4];
            float4 e1 = *(const float4*)&Ea[wv][2 * li + 1][hq * 4];
            float4 f0 = *(const float4*)&Em[wv][2 * lj    ][hq * 4];
            float4 f1 = *(const float4*)&Em[wv][2 * lj + 1][hq * 4];
            float4 w4 = *(const float4*)&wl[hb0 + hh + hq * 4];  // broadcast
            #define PKQUAD(DA, DB, WH, ACCA, ACCB)                   \
            {                                                        \
                f32x2 Q  = DA * DB;                                  \
                float pr = Q.x * Q.y;                                \
                float R  = fast_rcp(pr);                             \
                float RW = R * (WH);                                 \
                f32x2 T  = (f32x2){Q.y, Q.x} * RW;                   \
                ACCA = __builtin_elementwise_fma(T, DB, ACCA);       \
                ACCB = __builtin_elementwise_fma(T, DA, ACCB);       \
            }
            #define HSTEP(H, S)                                                     \
            {                                                                       \
                f32x2 F  = {f0.H, f1.H};                                            \
                f32x2 D0 = __builtin_elementwise_fma((f32x2){e0.H, e0.H}, F, one2); \
                f32x2 D1 = __builtin_elementwise_fma((f32x2){e1.H, e1.H}, F, one2); \
                PKQUAD(D0, D1, w4.H, accA[S], accB[S])                              \
            }
            HSTEP(x, 0) HSTEP(y, 1) HSTEP(z, 0) HSTEP(w, 1)
            #undef HSTEP
            #undef PKQUAD
        }
    }

    f32x2 s0 = accA[0] + accA[1];
    f32x2 s1 = accB[0] + accB[1];

    float* partial = (float*)Ea;
    __syncthreads();
    if (wv >= 1) {
        float* p = partial + (wv - 1) * 256 + lane * 4;
        p[0] = s0.x; p[1] = s0.y; p[2] = s1.x; p[3] = s1.y;
    }
    __syncthreads();
    if (wv == 0) {
        const float base = lsum + outBias[0];
        float t00 = s0.x, t01 = s0.y, t10 = s1.x, t11 = s1.y;
        #pragma unroll
        for (int q = 0; q < 3; ++q) {
            const float* p = partial + q * 256 + lane * 4;
            t00 += p[0]; t01 += p[1]; t10 += p[2]; t11 += p[3];
        }
        const int gi = i0 + 2 * li, gj = j0 + 2 * lj;
        float2 o0, o1;
        o0.x = fmaf(-2.f, t00, base);
        o0.y = fmaf(-2.f, t01, base);
        o1.x = fmaf(-2.f, t10, base);
        o1.y = fmaf(-2.f, t11, base);
        *(float2*)&out[gi * TT + gj]       = o0;
        *(float2*)&out[(gi + 1) * TT + gj] = o1;
    }
}

extern "C" void kernel_launch(void* const* d_in, const int* in_sizes, int n_in,
                              void* d_out, int out_size, void* d_ws, size_t ws_size,
                              hipStream_t stream) {
    const float* x        = (const float*)d_in[0];
    const float* foh      = (const float*)d_in[1];
    const float* fom      = (const float*)d_in[2];
    const float* catBias  = (const float*)d_in[3];
    const float* hid2     = (const float*)d_in[4];
    const float* hid2Bias = (const float*)d_in[5];
    const float* outLayer = (const float*)d_in[6];
    const float* outBias  = (const float*)d_in[7];
    float* out = (float*)d_out;

    char* wsb = (char*)d_ws;
    float*  pw  = (float*)(wsb);                        // 768*1024*4
    ushort* act = (ushort*)(wsb + 3145728);             // 768*1024*2
    ushort* xb  = (ushort*)(wsb + 4718592);             // 768*512*2
    ushort* b1t = (ushort*)(wsb + 5505024);             // 1024*512*2
    ushort* h2t = (ushort*)(wsb + 6553600);             // 512*1024*2

    // Attempt fused cooperative front; fall back to 3 separate kernels if
    // the runtime rejects cooperative launch (e.g. under graph capture).
    void* args[] = {(void*)&x, (void*)&foh, (void*)&fom, (void*)&hid2,
                    (void*)&catBias, (void*)&hid2Bias,
                    (void*)&xb, (void*)&b1t, (void*)&h2t, (void*)&act, (void*)&pw};
    hipError_t ce = hipLaunchCooperativeKernel((const void*)k_front,
                                               dim3(768), dim3(256),
                                               args, 0, stream);
    if (ce != hipSuccess) {
        (void)hipGetLastError();   // clear sticky error, continue capture
        k_prep <<<dim3(1408),    64, 0, stream>>>(x, foh, fom, hid2, xb, b1t, h2t);
        k_gemm1<<<dim3(32, 24), 128, 0, stream>>>(xb, b1t, catBias, act);
        k_gemm2<<<dim3(32, 24), 128, 0, stream>>>(act, h2t, hid2Bias, pw);
    }
    k_pair <<<dim3(2304),   256, 0, stream>>>(pw, outLayer, outBias, out);
}

// Round 18
// 55.438 us; speedup vs baseline: 4.5344x; 4.5344x over previous
//
#include <hip/hip_runtime.h>

#define TT 768
#define KD 512
#define NC 1024
#define RLN2_2 2.8853900817779268f   // 2/ln(2)

typedef short short8 __attribute__((ext_vector_type(8)));
typedef float f32x4  __attribute__((ext_vector_type(4)));
typedef float f32x2  __attribute__((ext_vector_type(2)));

__device__ __forceinline__ float fast_exp2(float x) {
#if __has_builtin(__builtin_amdgcn_exp2f)
    return __builtin_amdgcn_exp2f(x);
#else
    return exp2f(x);
#endif
}
__device__ __forceinline__ float fast_rcp(float x) {
#if __has_builtin(__builtin_amdgcn_rcpf)
    return __builtin_amdgcn_rcpf(x);
#else
    return 1.0f / x;
#endif
}
__device__ __forceinline__ float fast_tanh(float x) {
    float e = fast_exp2(x * RLN2_2);
    return fmaf(-2.0f, fast_rcp(e + 1.0f), 1.0f);
}
__device__ __forceinline__ ushort f2bf(float f) {   // RNE f32->bf16
    uint u = __float_as_uint(f);
    u += 0x7fff + ((u >> 16) & 1);
    return (ushort)(u >> 16);
}

// ---------------------------------------------------------------------------
// GEMM1 (fused prep): act = tanh( x @ (foh|fom) + catBias ), bf16 out.
// A fragments: DIRECT from x f32 (k-contiguous) + convert in regs.
// B fragments: per-wave LDS transpose staging of a [32k][32n] f32 chunk
//   ([32][33] pad; col reads are <=2-way bank aliases = free), cvt in regs.
// 32x32 tile / block, 2-wave K-split (kv sums k in [kv*256,+256)),
// wave-private staging => no in-loop barriers. Grid 32x24 = 768 blocks.
// ---------------------------------------------------------------------------
__global__ __launch_bounds__(128) void k_gemm1(
    const float* __restrict__ x, const float* __restrict__ foh,
    const float* __restrict__ fom, const float* __restrict__ catBias,
    ushort* __restrict__ act)
{
    __shared__ float ps[64][20];
    __shared__ float bt[2][32][33];

    const int t = threadIdx.x;
    const int kv = t >> 6, lane = t & 63;
    const int n0 = blockIdx.x * 32;
    const int m0 = blockIdx.y * 32;
    const float* B = (n0 < 512) ? foh : fom;
    const int nc0  = (n0 < 512) ? n0 : n0 - 512;
    const int lrow = lane & 15, lk = (lane >> 4) * 8;
    const int kbase = kv * 256;

    // B staging geometry: 64 lanes cover 32 rows x 32 cols, 16 floats/lane
    const int skr = lane >> 1;           // k-row 0..31
    const int snc = (lane & 1) * 16;     // col 0 or 16

    const float* px0 = &x[(m0 + lrow) * KD + kbase + lk];
    const float* px1 = px0 + 16 * KD;

    f32x4 acc[2][2] = {};
    #pragma unroll 1
    for (int c = 0; c < 8; ++c) {
        const int k0 = kbase + c * 32;
        // ---- stage B chunk (wave-private; in-order DS pipe) ----
        const float* bsrc = &B[(k0 + skr) * 512 + nc0 + snc];
        float4 s0 = *(const float4*)(bsrc);
        float4 s1 = *(const float4*)(bsrc + 4);
        float4 s2 = *(const float4*)(bsrc + 8);
        float4 s3 = *(const float4*)(bsrc + 12);
        *(float4*)&bt[kv][skr][snc]      = s0;
        *(float4*)&bt[kv][skr][snc + 4]  = s1;
        *(float4*)&bt[kv][skr][snc + 8]  = s2;
        *(float4*)&bt[kv][skr][snc + 12] = s3;
        // ---- A fragments direct from x (f32 -> bf16) ----
        float4 a00 = *(const float4*)(px0 + c * 32);
        float4 a01 = *(const float4*)(px0 + c * 32 + 4);
        float4 a10 = *(const float4*)(px1 + c * 32);
        float4 a11 = *(const float4*)(px1 + c * 32 + 4);
        short8 af0, af1;
        af0[0] = (short)f2bf(a00.x); af0[1] = (short)f2bf(a00.y);
        af0[2] = (short)f2bf(a00.z); af0[3] = (short)f2bf(a00.w);
        af0[4] = (short)f2bf(a01.x); af0[5] = (short)f2bf(a01.y);
        af0[6] = (short)f2bf(a01.z); af0[7] = (short)f2bf(a01.w);
        af1[0] = (short)f2bf(a10.x); af1[1] = (short)f2bf(a10.y);
        af1[2] = (short)f2bf(a10.z); af1[3] = (short)f2bf(a10.w);
        af1[4] = (short)f2bf(a11.x); af1[5] = (short)f2bf(a11.y);
        af1[6] = (short)f2bf(a11.z); af1[7] = (short)f2bf(a11.w);
        // ---- B fragments from LDS columns (after own writes; in-order) ----
        short8 bf0, bf1;
        #pragma unroll
        for (int q = 0; q < 8; ++q) {
            bf0[q] = (short)f2bf(bt[kv][lk + q][lrow]);
            bf1[q] = (short)f2bf(bt[kv][lk + q][lrow + 16]);
        }
        acc[0][0] = __builtin_amdgcn_mfma_f32_16x16x32_bf16(af0, bf0, acc[0][0], 0, 0, 0);
        acc[0][1] = __builtin_amdgcn_mfma_f32_16x16x32_bf16(af0, bf1, acc[0][1], 0, 0, 0);
        acc[1][0] = __builtin_amdgcn_mfma_f32_16x16x32_bf16(af1, bf0, acc[1][0], 0, 0, 0);
        acc[1][1] = __builtin_amdgcn_mfma_f32_16x16x32_bf16(af1, bf1, acc[1][1], 0, 0, 0);
    }
    if (kv == 1) {
        *(f32x4*)&ps[lane][0]  = acc[0][0];
        *(f32x4*)&ps[lane][4]  = acc[0][1];
        *(f32x4*)&ps[lane][8]  = acc[1][0];
        *(f32x4*)&ps[lane][12] = acc[1][1];
    }
    __syncthreads();
    if (kv == 0) {
        acc[0][0] += *(const f32x4*)&ps[lane][0];
        acc[0][1] += *(const f32x4*)&ps[lane][4];
        acc[1][0] += *(const f32x4*)&ps[lane][8];
        acc[1][1] += *(const f32x4*)&ps[lane][12];
        const int crow = (lane >> 4) * 4, ccol = lane & 15;
        #pragma unroll
        for (int nf = 0; nf < 2; ++nf) {
            int col = n0 + nf * 16 + ccol;
            float cb = catBias[col];
            #pragma unroll
            for (int mf = 0; mf < 2; ++mf) {
                #pragma unroll
                for (int r = 0; r < 4; ++r) {
                    int row = m0 + mf * 16 + crow + r;
                    act[row * NC + col] = f2bf(fast_tanh(acc[mf][nf][r] + cb));
                }
            }
        }
    }
}

// ---------------------------------------------------------------------------
// GEMM2 (fused prep) + exp epilogue -> pw = EA | EM (f32).
// A = act direct bf16 fragments; B = hid2 transposed on the fly via the same
// per-wave LDS staging. Same tiling / K-split as gemm1.
// ---------------------------------------------------------------------------
__global__ __launch_bounds__(128) void k_gemm2(
    const ushort* __restrict__ act, const float* __restrict__ hid2,
    const float* __restrict__ hid2Bias, float* __restrict__ pw)
{
    __shared__ float ps[64][20];
    __shared__ float bt[2][32][33];

    const int t = threadIdx.x;
    const int kv = t >> 6, lane = t & 63;
    const int n0 = blockIdx.x * 32;
    const int m0 = blockIdx.y * 32;
    const bool top = (blockIdx.x < 16);
    const int koff = top ? 0 : 512;
    const int nc0  = top ? n0 : n0 - 512;
    const int lrow = lane & 15, lk = (lane >> 4) * 8;
    const int kbase = kv * 256;

    const int skr = lane >> 1;
    const int snc = (lane & 1) * 16;

    const ushort* pa0 = &act[(m0 + lrow) * NC + koff + kbase + lk];
    const ushort* pa1 = pa0 + 16 * NC;

    f32x4 acc[2][2] = {};
    #pragma unroll 1
    for (int c = 0; c < 8; ++c) {
        const int k0 = kbase + c * 32;
        // ---- stage B chunk from hid2 (rows koff+k, cols nc0..) ----
        const float* bsrc = &hid2[(koff + k0 + skr) * 512 + nc0 + snc];
        float4 s0 = *(const float4*)(bsrc);
        float4 s1 = *(const float4*)(bsrc + 4);
        float4 s2 = *(const float4*)(bsrc + 8);
        float4 s3 = *(const float4*)(bsrc + 12);
        *(float4*)&bt[kv][skr][snc]      = s0;
        *(float4*)&bt[kv][skr][snc + 4]  = s1;
        *(float4*)&bt[kv][skr][snc + 8]  = s2;
        *(float4*)&bt[kv][skr][snc + 12] = s3;
        // ---- A fragments direct (bf16) ----
        short8 af0 = *(const short8*)(pa0 + c * 32);
        short8 af1 = *(const short8*)(pa1 + c * 32);
        // ---- B fragments from LDS columns ----
        short8 bf0, bf1;
        #pragma unroll
        for (int q = 0; q < 8; ++q) {
            bf0[q] = (short)f2bf(bt[kv][lk + q][lrow]);
            bf1[q] = (short)f2bf(bt[kv][lk + q][lrow + 16]);
        }
        acc[0][0] = __builtin_amdgcn_mfma_f32_16x16x32_bf16(af0, bf0, acc[0][0], 0, 0, 0);
        acc[0][1] = __builtin_amdgcn_mfma_f32_16x16x32_bf16(af0, bf1, acc[0][1], 0, 0, 0);
        acc[1][0] = __builtin_amdgcn_mfma_f32_16x16x32_bf16(af1, bf0, acc[1][0], 0, 0, 0);
        acc[1][1] = __builtin_amdgcn_mfma_f32_16x16x32_bf16(af1, bf1, acc[1][1], 0, 0, 0);
    }
    if (kv == 1) {
        *(f32x4*)&ps[lane][0]  = acc[0][0];
        *(f32x4*)&ps[lane][4]  = acc[0][1];
        *(f32x4*)&ps[lane][8]  = acc[1][0];
        *(f32x4*)&ps[lane][12] = acc[1][1];
    }
    __syncthreads();
    if (kv == 0) {
        acc[0][0] += *(const f32x4*)&ps[lane][0];
        acc[0][1] += *(const f32x4*)&ps[lane][4];
        acc[1][0] += *(const f32x4*)&ps[lane][8];
        acc[1][1] += *(const f32x4*)&ps[lane][12];
        const int crow = (lane >> 4) * 4, ccol = lane & 15;
        #pragma unroll
        for (int nf = 0; nf < 2; ++nf) {
            int col = n0 + nf * 16 + ccol;
            float hb = top ? hid2Bias[col] : 0.0f;
            #pragma unroll
            for (int mf = 0; mf < 2; ++mf) {
                #pragma unroll
                for (int r = 0; r < 4; ++r) {
                    int row = m0 + mf * 16 + crow + r;
                    pw[row * NC + col] = fast_exp2(RLN2_2 * (acc[mf][nf][r] + hb));
                }
            }
        }
    }
}

// ---------------------------------------------------------------------------
// Pairwise [FROZEN = r15 best]: 16x16 tile / 4-wave h-split / wave-private
// staging / no main-loop barriers / packed f32x2 math / w in LDS.
// Grid 2304 XCD-swz x 4 waves; VGPR <= 64 -> 32 waves/CU resident.
// ---------------------------------------------------------------------------
__global__ __launch_bounds__(256) void k_pair(
    const float* __restrict__ pw, const float* __restrict__ w,
    const float* __restrict__ outBias, float* __restrict__ out)
{
    __shared__ float Ea[4][16][18];
    __shared__ float Em[4][16][18];
    __shared__ float wl[512];

    const int t    = threadIdx.x;
    const int wv   = t >> 6, lane = t & 63;
    const int bid  = blockIdx.x;
    const int sw   = (bid & 7) * 288 + (bid >> 3);   // XCD swizzle (8 | 2304)
    const int it = sw / 48, jt = sw % 48;
    const int i0 = it * 16, j0 = jt * 16;
    const int hb0 = wv * 128;                        // this wave's h-quarter

    *(float2*)&wl[hb0 + lane * 2] = *(const float2*)&w[hb0 + lane * 2];
    float4 wa = *(const float4*)&w[lane * 8];
    float4 wb = *(const float4*)&w[lane * 8 + 4];
    float lsum = (wa.x + wa.y) + (wa.z + wa.w) + (wb.x + wb.y) + (wb.z + wb.w);
    #pragma unroll
    for (int d = 1; d < 64; d <<= 1) lsum += __shfl_xor(lsum, d, 64);

    const int sr = lane >> 2;            // 0..15
    const int sc = (lane & 3) * 4;       // 0..12
    const float* srcA = &pw[(i0 + sr) * NC + hb0 + sc];
    const float* srcM = &pw[(j0 + sr) * NC + 512 + hb0 + sc];

    const int li = lane >> 3, lj = lane & 7;

    float4 fa = *(const float4*)(srcA);
    float4 fm = *(const float4*)(srcM);

    const f32x2 one2 = {1.0f, 1.0f};
    f32x2 accA[2] = {}, accB[2] = {};

    #pragma unroll 1
    for (int c = 0; c < 8; ++c) {        // 8 chunks x 16 h
        const int hh = c * 16;
        *(float4*)&Ea[wv][sr][sc] = fa;  // wave-private; in-order DS pipe
        *(float4*)&Em[wv][sr][sc] = fm;
        if (c < 7) {
            fa = *(const float4*)(srcA + hh + 16);
            fm = *(const float4*)(srcM + hh + 16);
        }
        #pragma unroll
        for (int hq = 0; hq < 4; ++hq) {
            float4 e0 = *(const float4*)&Ea[wv][2 * li    ][hq * 4];
            float4 e1 = *(const float4*)&Ea[wv][2 * li + 1][hq * 4];
            float4 f0 = *(const float4*)&Em[wv][2 * lj    ][hq * 4];
            float4 f1 = *(const float4*)&Em[wv][2 * lj + 1][hq * 4];
            float4 w4 = *(const float4*)&wl[hb0 + hh + hq * 4];  // broadcast
            #define PKQUAD(DA, DB, WH, ACCA, ACCB)                   \
            {                                                        \
                f32x2 Q  = DA * DB;                                  \
                float pr = Q.x * Q.y;                                \
                float R  = fast_rcp(pr);                             \
                float RW = R * (WH);                                 \
                f32x2 T  = (f32x2){Q.y, Q.x} * RW;                   \
                ACCA = __builtin_elementwise_fma(T, DB, ACCA);       \
                ACCB = __builtin_elementwise_fma(T, DA, ACCB);       \
            }
            #define HSTEP(H, S)                                                     \
            {                                                                       \
                f32x2 F  = {f0.H, f1.H};                                            \
                f32x2 D0 = __builtin_elementwise_fma((f32x2){e0.H, e0.H}, F, one2); \
                f32x2 D1 = __builtin_elementwise_fma((f32x2){e1.H, e1.H}, F, one2); \
                PKQUAD(D0, D1, w4.H, accA[S], accB[S])                              \
            }
            HSTEP(x, 0) HSTEP(y, 1) HSTEP(z, 0) HSTEP(w, 1)
            #undef HSTEP
            #undef PKQUAD
        }
    }

    f32x2 s0 = accA[0] + accA[1];
    f32x2 s1 = accB[0] + accB[1];

    float* partial = (float*)Ea;
    __syncthreads();
    if (wv >= 1) {
        float* p = partial + (wv - 1) * 256 + lane * 4;
        p[0] = s0.x; p[1] = s0.y; p[2] = s1.x; p[3] = s1.y;
    }
    __syncthreads();
    if (wv == 0) {
        const float base = lsum + outBias[0];
        float t00 = s0.x, t01 = s0.y, t10 = s1.x, t11 = s1.y;
        #pragma unroll
        for (int q = 0; q < 3; ++q) {
            const float* p = partial + q * 256 + lane * 4;
            t00 += p[0]; t01 += p[1]; t10 += p[2]; t11 += p[3];
        }
        const int gi = i0 + 2 * li, gj = j0 + 2 * lj;
        float2 o0, o1;
        o0.x = fmaf(-2.f, t00, base);
        o0.y = fmaf(-2.f, t01, base);
        o1.x = fmaf(-2.f, t10, base);
        o1.y = fmaf(-2.f, t11, base);
        *(float2*)&out[gi * TT + gj]       = o0;
        *(float2*)&out[(gi + 1) * TT + gj] = o1;
    }
}

extern "C" void kernel_launch(void* const* d_in, const int* in_sizes, int n_in,
                              void* d_out, int out_size, void* d_ws, size_t ws_size,
                              hipStream_t stream) {
    const float* x        = (const float*)d_in[0];
    const float* foh      = (const float*)d_in[1];
    const float* fom      = (const float*)d_in[2];
    const float* catBias  = (const float*)d_in[3];
    const float* hid2     = (const float*)d_in[4];
    const float* hid2Bias = (const float*)d_in[5];
    const float* outLayer = (const float*)d_in[6];
    const float* outBias  = (const float*)d_in[7];
    float* out = (float*)d_out;

    char* wsb = (char*)d_ws;
    float*  pw  = (float*)(wsb);                        // 768*1024*4
    ushort* act = (ushort*)(wsb + 3145728);             // 768*1024*2

    k_gemm1<<<dim3(32, 24), 128, 0, stream>>>(x, foh, fom, catBias, act);
    k_gemm2<<<dim3(32, 24), 128, 0, stream>>>(act, hid2, hid2Bias, pw);
    k_pair <<<dim3(2304),   256, 0, stream>>>(pw, outLayer, outBias, out);
}